// Round 1
// baseline (421.962 us; speedup 1.0000x reference)
//
#include <hip/hip_runtime.h>

#define B_ 4
#define N0_ 50000
#define N1_ 25000
#define N2_ 12500
#define E0_ 800000
#define E1_ 400000
#define CIN_ 32
#define CS_ 16
#define COUT_ 32
#define EPS_ 1e-5f

__device__ __forceinline__ float sigmoidf_(float x) {
    return 1.0f / (1.0f + __expf(-x));
}

// ---- prep: derived weight vectors (qv = Q@Watt[0:C], kv = K@Watt[C:2C], se = We . Watt[2C:3C]) ----
__global__ void prep_kernel(const float* __restrict__ Q1, const float* __restrict__ K1,
                            const float* __restrict__ Watt1,
                            const float* __restrict__ Q2, const float* __restrict__ K2,
                            const float* __restrict__ Watt2,
                            const float* __restrict__ We1, const float* __restrict__ We2,
                            float* __restrict__ qv1, float* __restrict__ kv1,
                            float* __restrict__ qv2, float* __restrict__ kv2,
                            float* __restrict__ se) {
    int t = threadIdx.x;
    if (t < CS_) {
        float q = 0.f, k = 0.f;
        for (int c = 0; c < CS_; ++c) {
            q += Q1[t * CS_ + c] * Watt1[c];
            k += K1[t * CS_ + c] * Watt1[CS_ + c];
        }
        qv1[t] = q; kv1[t] = k;
    }
    if (t < COUT_) {
        float q = 0.f, k = 0.f;
        for (int c = 0; c < COUT_; ++c) {
            q += Q2[t * COUT_ + c] * Watt2[c];
            k += K2[t * COUT_ + c] * Watt2[COUT_ + c];
        }
        qv2[t] = q; kv2[t] = k;
    }
    if (t == 0) {
        float s1 = 0.f, s2 = 0.f;
        for (int c = 0; c < CS_; ++c) s1 += We1[c] * Watt1[2 * CS_ + c];
        for (int c = 0; c < COUT_; ++c) s2 += We2[c] * Watt2[2 * COUT_ + c];
        se[0] = s1; se[1] = s2;
    }
}

// ---- layer1 node transform: xs1[b,n,:] = X[b,n,:]@Wn1 (n<N1), xd1[b,n,:] = X[b,res0[n],:]@Wn1 ----
__global__ void node_xform1(const float* __restrict__ X, const int* __restrict__ res,
                            const float* __restrict__ Wn,
                            float* __restrict__ xs, float* __restrict__ xd) {
    int idx = blockIdx.x * blockDim.x + threadIdx.x;
    const int total = B_ * N1_ * CS_;
    if (idx >= total) return;
    int c = idx & (CS_ - 1);
    int n = (idx / CS_) % N1_;
    int b = idx / (CS_ * N1_);
    const float* xrs = X + ((size_t)b * N0_ + n) * CIN_;
    const float* xrd = X + ((size_t)b * N0_ + res[n]) * CIN_;
    float s = 0.f, d = 0.f;
#pragma unroll
    for (int k = 0; k < CIN_; ++k) {
        float w = Wn[k * CS_ + c];
        s += xrs[k] * w;
        d += xrd[k] * w;
    }
    xs[idx] = s;
    xd[idx] = d;
}

// ---- layer1 edge kernel: one wave per edge; lane = b*16 + c ----
__global__ void edge_kernel1(const int* __restrict__ ei, const float* __restrict__ ew,
                             const float* __restrict__ xs, const float* __restrict__ xd,
                             const float* __restrict__ qv, const float* __restrict__ kv,
                             const float* __restrict__ se, const float* __restrict__ We,
                             const float* __restrict__ batt, float* __restrict__ aggr) {
    int lane = threadIdx.x & 63;
    int wid = blockIdx.x * (blockDim.x >> 6) + (threadIdx.x >> 6);
    int nw = gridDim.x * (blockDim.x >> 6);
    int b = lane >> 4;
    int c = lane & 15;
    float qvc = qv[c], kvc = kv[c], wec = We[c];
    float se1 = se[0], b0 = batt[0];
    for (int e = wid; e < E0_; e += nw) {
        int src = ei[e];
        int dst = ei[E0_ + e];
        float w = ew[e];
        float xj = xs[((size_t)b * N1_ + src) * CS_ + c];
        float xi = xd[((size_t)b * N1_ + dst) * CS_ + c];
        float p = xj * qvc + xi * kvc;
        p += __shfl_xor(p, 1);
        p += __shfl_xor(p, 2);
        p += __shfl_xor(p, 4);
        p += __shfl_xor(p, 8);
        float att = sigmoidf_(p + w * se1 + b0);
        float gate = sigmoidf_(w * wec);
        atomicAdd(&aggr[((size_t)b * N1_ + dst) * CS_ + c], att * xj * gate);
    }
}

// ---- layer1 epilogue: per-node concat GEMM + norm(axis 0,2; ddof=1) + residual + leaky ----
__global__ void epilogue1(const float* __restrict__ xd, const float* __restrict__ ag,
                          const float* __restrict__ Wc, const float* __restrict__ bc,
                          float* __restrict__ h) {
    int lane = threadIdx.x & 63;
    int n = blockIdx.x * (blockDim.x >> 6) + (threadIdx.x >> 6);
    if (n >= N1_) return;
    int b = lane >> 4;
    int c = lane & 15;
    size_t base = ((size_t)b * N1_ + n) * CS_ + c;
    float xv = xd[base];
    float av = ag[base];
    float o = bc[c];
#pragma unroll
    for (int k = 0; k < CS_; ++k) {
        o += __shfl(xv, k, 16) * Wc[k * CS_ + c];
        o += __shfl(av, k, 16) * Wc[(CS_ + k) * CS_ + c];
    }
    float s = o, sq = o * o;
#pragma unroll
    for (int m = 1; m < 64; m <<= 1) {
        s += __shfl_xor(s, m);
        sq += __shfl_xor(sq, m);
    }
    float mean = s * (1.f / 64.f);
    float var = (sq - 64.f * mean * mean) * (1.f / 63.f);
    float inv = rsqrtf(var + EPS_);
    float v = xv + (o - mean) * inv;
    h[base] = v > 0.f ? v : 0.01f * v;
}

// ---- layer2 node transform: xs2[b,n,:] = h[b,n,:]@Wn2 (n<N2), xd2[b,n,:] = h[b,res1[n],:]@Wn2 ----
__global__ void node_xform2(const float* __restrict__ H, const int* __restrict__ res,
                            const float* __restrict__ Wn,
                            float* __restrict__ xs, float* __restrict__ xd) {
    int idx = blockIdx.x * blockDim.x + threadIdx.x;
    const int total = B_ * N2_ * COUT_;
    if (idx >= total) return;
    int c = idx & (COUT_ - 1);
    int n = (idx / COUT_) % N2_;
    int b = idx / (COUT_ * N2_);
    const float* hs = H + ((size_t)b * N1_ + n) * CS_;
    const float* hd = H + ((size_t)b * N1_ + res[n]) * CS_;
    float s = 0.f, d = 0.f;
#pragma unroll
    for (int k = 0; k < CS_; ++k) {
        float w = Wn[k * COUT_ + c];
        s += hs[k] * w;
        d += hd[k] * w;
    }
    xs[idx] = s;
    xd[idx] = d;
}

// ---- layer2 edge kernel: one wave per edge; lane = bl*32 + c, loops b = bl, bl+2 ----
__global__ void edge_kernel2(const int* __restrict__ ei, const float* __restrict__ ew,
                             const float* __restrict__ xs, const float* __restrict__ xd,
                             const float* __restrict__ qv, const float* __restrict__ kv,
                             const float* __restrict__ se2, const float* __restrict__ We,
                             const float* __restrict__ batt, float* __restrict__ aggr) {
    int lane = threadIdx.x & 63;
    int wid = blockIdx.x * (blockDim.x >> 6) + (threadIdx.x >> 6);
    int nw = gridDim.x * (blockDim.x >> 6);
    int bl = lane >> 5;
    int c = lane & 31;
    float qvc = qv[c], kvc = kv[c], wec = We[c];
    float sev = se2[0], b0 = batt[0];
    for (int e = wid; e < E1_; e += nw) {
        int src = ei[e];
        int dst = ei[E1_ + e];
        float w = ew[e];
        float gate = sigmoidf_(w * wec);
        float base_att = w * sev + b0;
#pragma unroll
        for (int j = 0; j < 2; ++j) {
            int b = bl + 2 * j;
            float xj = xs[((size_t)b * N2_ + src) * COUT_ + c];
            float xi = xd[((size_t)b * N2_ + dst) * COUT_ + c];
            float p = xj * qvc + xi * kvc;
            p += __shfl_xor(p, 1);
            p += __shfl_xor(p, 2);
            p += __shfl_xor(p, 4);
            p += __shfl_xor(p, 8);
            p += __shfl_xor(p, 16);
            float att = sigmoidf_(p + base_att);
            atomicAdd(&aggr[((size_t)b * N2_ + dst) * COUT_ + c], att * xj * gate);
        }
    }
}

// ---- layer2 epilogue -> d_out ----
__global__ void epilogue2(const float* __restrict__ xd, const float* __restrict__ ag,
                          const float* __restrict__ Wc, const float* __restrict__ bc,
                          float* __restrict__ out) {
    int lane = threadIdx.x & 63;
    int n = blockIdx.x * (blockDim.x >> 6) + (threadIdx.x >> 6);
    if (n >= N2_) return;
    int c = lane & 31;
    int bl = lane >> 5;
    size_t base0 = ((size_t)bl * N2_ + n) * COUT_ + c;
    size_t base1 = ((size_t)(bl + 2) * N2_ + n) * COUT_ + c;
    float xv0 = xd[base0], xv1 = xd[base1];
    float av0 = ag[base0], av1 = ag[base1];
    float o0 = bc[c], o1 = o0;
#pragma unroll
    for (int k = 0; k < COUT_; ++k) {
        float w1 = Wc[k * COUT_ + c];
        float w2 = Wc[(COUT_ + k) * COUT_ + c];
        o0 += __shfl(xv0, k, 32) * w1 + __shfl(av0, k, 32) * w2;
        o1 += __shfl(xv1, k, 32) * w1 + __shfl(av1, k, 32) * w2;
    }
    float s = o0 + o1, sq = o0 * o0 + o1 * o1;
#pragma unroll
    for (int m = 1; m < 64; m <<= 1) {
        s += __shfl_xor(s, m);
        sq += __shfl_xor(sq, m);
    }
    float mean = s * (1.f / 128.f);
    float var = (sq - 128.f * mean * mean) * (1.f / 127.f);
    float inv = rsqrtf(var + EPS_);
    float v0 = xv0 + (o0 - mean) * inv;
    float v1 = xv1 + (o1 - mean) * inv;
    out[base0] = v0 > 0.f ? v0 : 0.01f * v0;
    out[base1] = v1 > 0.f ? v1 : 0.01f * v1;
}

extern "C" void kernel_launch(void* const* d_in, const int* in_sizes, int n_in,
                              void* d_out, int out_size, void* d_ws, size_t ws_size,
                              hipStream_t stream) {
    (void)in_sizes; (void)n_in; (void)out_size; (void)ws_size;
    const float* X     = (const float*)d_in[0];
    const int*   ei0   = (const int*)d_in[1];
    const float* ew0   = (const float*)d_in[2];
    const int*   rn0   = (const int*)d_in[3];
    const int*   ei1   = (const int*)d_in[4];
    const float* ew1   = (const float*)d_in[5];
    const int*   rn1   = (const int*)d_in[6];
    const float* Wn1   = (const float*)d_in[7];
    const float* We1   = (const float*)d_in[8];
    const float* Q1    = (const float*)d_in[9];
    const float* K1    = (const float*)d_in[10];
    const float* Watt1 = (const float*)d_in[11];
    const float* batt1 = (const float*)d_in[12];
    const float* Wc1   = (const float*)d_in[13];
    const float* bc1   = (const float*)d_in[14];
    const float* Wn2   = (const float*)d_in[15];
    const float* We2   = (const float*)d_in[16];
    const float* Q2    = (const float*)d_in[17];
    const float* K2    = (const float*)d_in[18];
    const float* Watt2 = (const float*)d_in[19];
    const float* batt2 = (const float*)d_in[20];
    const float* Wc2   = (const float*)d_in[21];
    const float* bc2   = (const float*)d_in[22];

    // workspace layout: 4 aliased buffers of B*N1*CS == B*N2*COUT == 1.6M floats each
    const size_t BUF = (size_t)B_ * N1_ * CS_;  // == B_*N2_*COUT_
    float* ws = (float*)d_ws;
    float* P0 = ws;              // xs1, then h1
    float* P1 = P0 + BUF;        // xd1, then xs2
    float* P2 = P1 + BUF;        // ag1, then xd2
    float* P3 = P2 + BUF;        // ag2
    float* qv1 = P3 + BUF;
    float* kv1 = qv1 + 16;
    float* qv2 = kv1 + 16;
    float* kv2 = qv2 + 32;
    float* se  = kv2 + 32;       // se[0]=layer1, se[1]=layer2

    hipMemsetAsync(P2, 0, BUF * sizeof(float), stream);  // ag1
    hipMemsetAsync(P3, 0, BUF * sizeof(float), stream);  // ag2

    prep_kernel<<<1, 64, 0, stream>>>(Q1, K1, Watt1, Q2, K2, Watt2, We1, We2,
                                      qv1, kv1, qv2, kv2, se);

    // layer 1
    node_xform1<<<(B_ * N1_ * CS_ + 255) / 256, 256, 0, stream>>>(X, rn0, Wn1, P0, P1);
    edge_kernel1<<<4096, 256, 0, stream>>>(ei0, ew0, P0, P1, qv1, kv1, se, We1, batt1, P2);
    epilogue1<<<(N1_ + 3) / 4, 256, 0, stream>>>(P1, P2, Wc1, bc1, P0);  // h1 -> P0

    // layer 2
    node_xform2<<<(B_ * N2_ * COUT_ + 255) / 256, 256, 0, stream>>>(P0, rn1, Wn2, P1, P2);
    edge_kernel2<<<4096, 256, 0, stream>>>(ei1, ew1, P1, P2, qv2, kv2, se + 1, We2, batt2, P3);
    epilogue2<<<(N2_ + 3) / 4, 256, 0, stream>>>(P2, P3, Wc2, bc2, (float*)d_out);
}